// Round 2
// baseline (423.892 us; speedup 1.0000x reference)
//
#include <hip/hip_runtime.h>
#include <hip/hip_fp16.h>

#define MDIM 32
#define KDIM 8192
#define NDIM 8192
#define NT 256          // columns per workgroup
#define KC 512          // k-rows per workgroup
#define BK 32           // k-rows per tile
#define NTILES (KC / BK)

typedef _Float16 half2_t __attribute__((ext_vector_type(2)));

#if __has_builtin(__builtin_amdgcn_fdot2)
__device__ __forceinline__ float fdot2(half2_t a, half2_t b, float c) {
  return __builtin_amdgcn_fdot2(a, b, c, false);
}
#else
__device__ __forceinline__ float fdot2(half2_t a, half2_t b, float c) {
  return c + (float)a.x * (float)b.x + (float)a.y * (float)b.y;
}
#endif

__device__ __forceinline__ half2_t pk_f16(float a, float b) {
#if __has_builtin(__builtin_amdgcn_cvt_pkrtz)
  return __builtin_bit_cast(half2_t, __builtin_amdgcn_cvt_pkrtz(a, b));
#else
  half2_t r; r.x = (_Float16)a; r.y = (_Float16)b; return r;
#endif
}

// Fused Q4_0 fake-quant + skinny GEMM.
// grid = (NDIM/NT, KDIM/KC), block = 256.
__global__ __launch_bounds__(256) void fused_q4_gemm(
    const float* __restrict__ x,      // [32][8192]
    const float* __restrict__ w,      // [8192][8192]
    const float* __restrict__ bias,   // [8192]
    float* __restrict__ out)          // [32][8192]
{
  // (scale, inv_d) per quant block of this tile, layout [nb][krow] -> nb*BK + krow
  __shared__ __align__(16) float2 s_scale[8 * BK];
  // x packed as half2 pairs along k: [kp][m], row stride 36 (pad to kill bank conflicts,
  // keeps 16B alignment: 36*4 = 144 = 9*16)
  __shared__ __align__(16) unsigned int s_x2[(BK / 2) * 36];

  const int t  = threadIdx.x;
  const int n0 = blockIdx.x * NT;
  const int k0 = blockIdx.y * KC;

  const int gn  = n0 + t;       // this lane's output column
  const int nb2 = t >> 5;       // which quant block (of 8) this column is in

  float acc[MDIM];
#pragma unroll
  for (int m = 0; m < MDIM; ++m) acc[m] = 0.0f;

  const int krow = t >> 3;      // phase-A mapping: one 32-elem block per thread
  const int nb   = t & 7;

  for (int tt = 0; tt < NTILES; ++tt) {
    const int kt = k0 + tt * BK;

    // ---------- Phase A: per-block scale (exact reference semantics) ----------
    {
      const float* bp = w + (size_t)(kt + krow) * NDIM + n0 + nb * 32;
      float best_abs = -1.0f, best_val = 0.0f;
#pragma unroll
      for (int j = 0; j < 8; ++j) {
        float4 v = reinterpret_cast<const float4*>(bp)[j];
        float a;
        a = fabsf(v.x); if (a > best_abs) { best_abs = a; best_val = v.x; }
        a = fabsf(v.y); if (a > best_abs) { best_abs = a; best_val = v.y; }
        a = fabsf(v.z); if (a > best_abs) { best_abs = a; best_val = v.z; }
        a = fabsf(v.w); if (a > best_abs) { best_abs = a; best_val = v.w; }
      }
      float d   = best_val * -0.125f;              // d = -max_val / 8 (exact)
      float inv = (d == 0.0f) ? 0.0f : 1.0f / d;   // exact fp32 divide, matches ref
      float sc  = __half2float(__float2half(d));   // fp16 RTNE round-trip
      s_scale[nb * BK + krow] = make_float2(sc, inv);
    }

    // ---------- stage x as half2 k-pairs: 16 kp x 32 m ----------
#pragma unroll
    for (int j = 0; j < 2; ++j) {
      int idx = t + j * 256;
      int kp  = idx & 15;
      int m   = idx >> 4;
      float2 xv = *reinterpret_cast<const float2*>(x + (size_t)m * KDIM + kt + 2 * kp);
      half2_t h = pk_f16(xv.x, xv.y);
      s_x2[kp * 36 + m] = __builtin_bit_cast(unsigned int, h);
    }

    __syncthreads();

    // ---------- Phase B: dequant + dot2 accumulate ----------
    const float* colp = w + (size_t)kt * NDIM + gn;
    const float4* svp = reinterpret_cast<const float4*>(s_scale) + nb2 * (BK / 2);
#pragma unroll
    for (int kp = 0; kp < BK / 2; ++kp) {
      float w0 = colp[(2 * kp) * NDIM];       // L1/L2 hit: phase A just pulled these lines
      float w1 = colp[(2 * kp + 1) * NDIM];
      float4 sv = svp[kp];                    // (sc0, inv0, sc1, inv1) broadcast
      float t0  = fmaf(w0, sv.y, 8.5f);
      float q0  = fminf(fmaxf(truncf(t0), 0.0f), 15.0f);
      float dq0 = (q0 - 8.0f) * sv.x;
      float t1  = fmaf(w1, sv.w, 8.5f);
      float q1  = fminf(fmaxf(truncf(t1), 0.0f), 15.0f);
      float dq1 = (q1 - 8.0f) * sv.z;
      half2_t w2 = pk_f16(dq0, dq1);
      const uint4* xrow = reinterpret_cast<const uint4*>(s_x2 + kp * 36);
#pragma unroll
      for (int g = 0; g < 8; ++g) {
        uint4 xq = xrow[g];                   // broadcast ds_read_b128 (4 m's)
        acc[4 * g + 0] = fdot2(w2, __builtin_bit_cast(half2_t, xq.x), acc[4 * g + 0]);
        acc[4 * g + 1] = fdot2(w2, __builtin_bit_cast(half2_t, xq.y), acc[4 * g + 1]);
        acc[4 * g + 2] = fdot2(w2, __builtin_bit_cast(half2_t, xq.z), acc[4 * g + 2]);
        acc[4 * g + 3] = fdot2(w2, __builtin_bit_cast(half2_t, xq.w), acc[4 * g + 3]);
      }
    }
    __syncthreads();
  }

  // ---------- write-out: k-split partials via atomics; split 0 adds bias ----------
  const float bv = (blockIdx.y == 0) ? bias[gn] : 0.0f;
#pragma unroll
  for (int m = 0; m < MDIM; ++m) {
    atomicAdd(out + (size_t)m * NDIM + gn, acc[m] + bv);
  }
}

extern "C" void kernel_launch(void* const* d_in, const int* in_sizes, int n_in,
                              void* d_out, int out_size, void* d_ws, size_t ws_size,
                              hipStream_t stream) {
  const float* x    = (const float*)d_in[0];   // inputs  [1,32,8192] f32
  const float* w    = (const float*)d_in[1];   // kernel  [8192,8192] f32
  const float* bias = (const float*)d_in[2];   // bias    [8192] f32
  float* out = (float*)d_out;                  // [1,32,8192] f32

  // d_out is poisoned before every call; zero it so atomic partials are correct.
  (void)hipMemsetAsync(out, 0, (size_t)MDIM * NDIM * sizeof(float), stream);

  dim3 grid(NDIM / NT, KDIM / KC);
  fused_q4_gemm<<<grid, 256, 0, stream>>>(x, w, bias, out);
}

// Round 3
// 372.365 us; speedup vs baseline: 1.1384x; 1.1384x over previous
//
#include <hip/hip_runtime.h>
#include <hip/hip_fp16.h>

#define MDIM 32
#define KDIM 8192
#define NDIM 8192
#define NT 128            // columns per workgroup
#define KC 512            // k-rows per workgroup (16 k-splits)
#define BK 64             // k-rows per tile
#define NTILES (KC / BK)  // 8
#define WPAD 132          // padded LDS row stride (words) for w2: 132 % 32 = 4

typedef _Float16 half2_t __attribute__((ext_vector_type(2)));

#if __has_builtin(__builtin_amdgcn_fdot2)
__device__ __forceinline__ float fdot2(half2_t a, half2_t b, float c) {
  return __builtin_amdgcn_fdot2(a, b, c, false);
}
#else
__device__ __forceinline__ float fdot2(half2_t a, half2_t b, float c) {
  return c + (float)a.x * (float)b.x + (float)a.y * (float)b.y;
}
#endif

__device__ __forceinline__ unsigned pk_u32(float a, float b) {
#if __has_builtin(__builtin_amdgcn_cvt_pkrtz)
  return __builtin_bit_cast(unsigned, __builtin_amdgcn_cvt_pkrtz(a, b));
#else
  half2_t r; r.x = (_Float16)a; r.y = (_Float16)b;
  return __builtin_bit_cast(unsigned, r);
#endif
}

__device__ __forceinline__ half2_t u2h(unsigned u) {
  return __builtin_bit_cast(half2_t, u);
}

// ---------- pre-pass: pack x[32][8192] f32 -> xp[4096][32] u32 (half2 along k) ----------
__global__ __launch_bounds__(256) void xpack_kernel(const float* __restrict__ x,
                                                    unsigned* __restrict__ xp) {
  __shared__ float sx[32][129];
  const int t  = threadIdx.x;
  const int k0 = blockIdx.x * 128;          // 64 WGs cover k
  {
    const int m = t >> 3, c = (t & 7) * 16;
    const float* p = x + (size_t)m * KDIM + k0 + c;
#pragma unroll
    for (int j = 0; j < 4; ++j) {
      float4 v = reinterpret_cast<const float4*>(p)[j];
      sx[m][c + j * 4 + 0] = v.x;
      sx[m][c + j * 4 + 1] = v.y;
      sx[m][c + j * 4 + 2] = v.z;
      sx[m][c + j * 4 + 3] = v.w;
    }
  }
  __syncthreads();
  const int kpl = t & 63, mh = t >> 6;      // mh in 0..3 -> 8 m's each
  unsigned pw[8];
#pragma unroll
  for (int j = 0; j < 8; ++j) {
    int mm = mh * 8 + j;
    pw[j] = pk_u32(sx[mm][2 * kpl], sx[mm][2 * kpl + 1]);
  }
  uint4* dst = reinterpret_cast<uint4*>(xp + ((size_t)(k0 >> 1) + kpl) * 32 + mh * 8);
  dst[0] = make_uint4(pw[0], pw[1], pw[2], pw[3]);
  dst[1] = make_uint4(pw[4], pw[5], pw[6], pw[7]);
}

// ---------- fused Q4_0 fake-quant + skinny GEMM ----------
// grid = (NDIM/NT, KDIM/KC) = (64,16), block = 256.
__global__ __launch_bounds__(256, 4) void fused_q4_gemm(
    const float* __restrict__ x,       // unused (kept for signature clarity)
    const unsigned* __restrict__ xp,   // [4096][32] half2-packed x
    const float* __restrict__ w,       // [8192][8192]
    const float* __restrict__ bias,    // [8192]
    float* __restrict__ out)           // [32][8192]
{
  __shared__ unsigned s_w2[32 * WPAD]; // 16.9 KB: [kp][n] half2 (k-pairs)

  const int t  = threadIdx.x;
  const int n0 = blockIdx.x * NT;
  const int k0 = blockIdx.y * KC;

  const int kr = t >> 3;               // k-pair row 0..31
  const int nc = t & 7;                // 16-col half-block 0..7
  const int n_local = t & 127;
  const int gn = n0 + n_local;
  // m-half: waves 0-1 -> m 0..15, waves 2-3 -> m 16..31 (wave-uniform via readfirstlane)
  const int mbase = (__builtin_amdgcn_readfirstlane(t) >> 7) << 4;

  float acc[16];
#pragma unroll
  for (int j = 0; j < 16; ++j) acc[j] = 0.0f;

  for (int tt = 0; tt < NTILES; ++tt) {
    const int kt = k0 + tt * BK;

    // ---- Phase A: load 2 rows x 16 cols, scales via half-block exchange, dequant, LDS ----
    {
      const float* rp = w + (size_t)(kt + 2 * kr) * NDIM + n0 + nc * 16;
      float4 v0[4], v1[4];
#pragma unroll
      for (int j = 0; j < 4; ++j) {
        v0[j] = reinterpret_cast<const float4*>(rp)[j];
        v1[j] = reinterpret_cast<const float4*>(rp + NDIM)[j];
      }
      // first-wins abs-argmax over this thread's 16 cols, per row
      float ba0 = -1.0f, bv0 = 0.0f, ba1 = -1.0f, bv1 = 0.0f;
#pragma unroll
      for (int j = 0; j < 4; ++j) {
        float c, a;
        c = v0[j].x; a = fabsf(c); if (a > ba0) { ba0 = a; bv0 = c; }
        c = v0[j].y; a = fabsf(c); if (a > ba0) { ba0 = a; bv0 = c; }
        c = v0[j].z; a = fabsf(c); if (a > ba0) { ba0 = a; bv0 = c; }
        c = v0[j].w; a = fabsf(c); if (a > ba0) { ba0 = a; bv0 = c; }
        c = v1[j].x; a = fabsf(c); if (a > ba1) { ba1 = a; bv1 = c; }
        c = v1[j].y; a = fabsf(c); if (a > ba1) { ba1 = a; bv1 = c; }
        c = v1[j].z; a = fabsf(c); if (a > ba1) { ba1 = a; bv1 = c; }
        c = v1[j].w; a = fabsf(c); if (a > ba1) { ba1 = a; bv1 = c; }
      }
      // combine with partner half-block (t^1). Even nc holds cols 0-15 (earlier: wins ties).
      float pa0 = __shfl_xor(ba0, 1), pv0 = __shfl_xor(bv0, 1);
      float pa1 = __shfl_xor(ba1, 1), pv1 = __shfl_xor(bv1, 1);
      const bool odd = (t & 1);
      if (odd ? (pa0 >= ba0) : (pa0 > ba0)) bv0 = pv0;
      if (odd ? (pa1 >= ba1) : (pa1 > ba1)) bv1 = pv1;

      float d0 = bv0 * -0.125f;
      float i0 = (d0 == 0.0f) ? 0.0f : 1.0f / d0;   // exact fp32 divide
      float s0 = __half2float(__float2half(d0));    // fp16 RTNE round-trip
      float d1 = bv1 * -0.125f;
      float i1 = (d1 == 0.0f) ? 0.0f : 1.0f / d1;
      float s1 = __half2float(__float2half(d1));

      unsigned pw[16];
#pragma unroll
      for (int j = 0; j < 4; ++j) {
        float q, a0f, a1f;
#define DQ(comp, idx)                                                      \
        q = fminf(fmaxf(truncf(fmaf(v0[j].comp, i0, 8.5f)), 0.0f), 15.0f); \
        a0f = (q - 8.0f) * s0;                                             \
        q = fminf(fmaxf(truncf(fmaf(v1[j].comp, i1, 8.5f)), 0.0f), 15.0f); \
        a1f = (q - 8.0f) * s1;                                             \
        pw[j * 4 + idx] = pk_u32(a0f, a1f);
        DQ(x, 0) DQ(y, 1) DQ(z, 2) DQ(w, 3)
#undef DQ
      }
      uint4* wp = reinterpret_cast<uint4*>(&s_w2[kr * WPAD + nc * 16]);
      wp[0] = make_uint4(pw[0],  pw[1],  pw[2],  pw[3]);
      wp[1] = make_uint4(pw[4],  pw[5],  pw[6],  pw[7]);
      wp[2] = make_uint4(pw[8],  pw[9],  pw[10], pw[11]);
      wp[3] = make_uint4(pw[12], pw[13], pw[14], pw[15]);
    }

    __syncthreads();

    // ---- Phase B: w2 from LDS (1 b32/kp), x from scalar loads, 16 dot2/kp ----
    const int kb = kt >> 1;
#pragma unroll 4
    for (int kp = 0; kp < BK / 2; ++kp) {
      half2_t w2 = u2h(s_w2[kp * WPAD + n_local]);
      const uint4* xr = reinterpret_cast<const uint4*>(xp + (size_t)(kb + kp) * 32 + mbase);
      uint4 q0 = xr[0], q1 = xr[1], q2 = xr[2], q3 = xr[3];
      acc[0]  = fdot2(w2, u2h(q0.x), acc[0]);
      acc[1]  = fdot2(w2, u2h(q0.y), acc[1]);
      acc[2]  = fdot2(w2, u2h(q0.z), acc[2]);
      acc[3]  = fdot2(w2, u2h(q0.w), acc[3]);
      acc[4]  = fdot2(w2, u2h(q1.x), acc[4]);
      acc[5]  = fdot2(w2, u2h(q1.y), acc[5]);
      acc[6]  = fdot2(w2, u2h(q1.z), acc[6]);
      acc[7]  = fdot2(w2, u2h(q1.w), acc[7]);
      acc[8]  = fdot2(w2, u2h(q2.x), acc[8]);
      acc[9]  = fdot2(w2, u2h(q2.y), acc[9]);
      acc[10] = fdot2(w2, u2h(q2.z), acc[10]);
      acc[11] = fdot2(w2, u2h(q2.w), acc[11]);
      acc[12] = fdot2(w2, u2h(q3.x), acc[12]);
      acc[13] = fdot2(w2, u2h(q3.y), acc[13]);
      acc[14] = fdot2(w2, u2h(q3.z), acc[14]);
      acc[15] = fdot2(w2, u2h(q3.w), acc[15]);
    }
    __syncthreads();
  }

  // ---- epilogue: k-split partials via atomics; split 0 folds bias ----
  const float bv = (blockIdx.y == 0) ? bias[gn] : 0.0f;
#pragma unroll
  for (int j = 0; j < 16; ++j) {
    atomicAdd(out + (size_t)(mbase + j) * NDIM + gn, acc[j] + bv);
  }
}

extern "C" void kernel_launch(void* const* d_in, const int* in_sizes, int n_in,
                              void* d_out, int out_size, void* d_ws, size_t ws_size,
                              hipStream_t stream) {
  const float* x    = (const float*)d_in[0];   // [1,32,8192] f32
  const float* w    = (const float*)d_in[1];   // [8192,8192] f32
  const float* bias = (const float*)d_in[2];   // [8192] f32
  float* out  = (float*)d_out;                 // [1,32,8192] f32
  unsigned* xp = (unsigned*)d_ws;              // 4096*32*4 = 512 KB

  (void)hipMemsetAsync(out, 0, (size_t)MDIM * NDIM * sizeof(float), stream);
  xpack_kernel<<<64, 256, 0, stream>>>(x, xp);

  dim3 grid(NDIM / NT, KDIM / KC);
  fused_q4_gemm<<<grid, 256, 0, stream>>>(x, xp, w, bias, out);
}